// Round 2
// baseline (292.735 us; speedup 1.0000x reference)
//
#include <hip/hip_runtime.h>

// RoIAlign via TF crop_and_resize. Fixed problem shapes:
//   featuremap (N=2, C=256, H=200, W=304) fp32
//   rois       (M=2048, 5) fp32  [batch_id, x1, y1, x2, y2]
//   out        (M, C, 7, 7) fp32
//
// R2: XCD-pinned channel groups (fetch 382->194 MB).
// R4: per-thread gather batch (123 us) — TA-bound: 32 scattered gathers/thread,
//     ~25 lines each; compiler serialized them (VGPR=32).
// R5: region staging, BC=8 (139 us) — right bytes/transactions, but VGPR=8
//     proves the staging loop compiled to serial load->vmcnt(0)->ds_write
//     round-trips; latency fully exposed, 2 barriers, 64K tiny blocks.
// R6: fix the pipelining, keep the staging:
//     * explicit float4 v[5] register batch: 5 independent loads issued
//       back-to-back, THEN 5 LDS writes (counted vmcnt drain) -> 5-deep MLP.
//     * BC=16 (block = 1 box x 16 ch): half the blocks, 5 loads/thread,
//       LDS channel stride 324 floats -> ds_write_b128 exactly bank-uniform.
//     * single barrier: every thread redundantly computes ys/xs (bit-exact
//       k=0 geometry), so staging never waits on the geometry phase.
#define RA_C   256
#define RA_H   200
#define RA_W   304
#define RA_HW  (RA_H * RA_W)        // 60800
#define RA_CHW (RA_C * RA_HW)       // 15564800
#define CROPN  7
#define CROP2  (CROPN * CROPN)      // 49
#define OUT_M  (RA_C * CROP2)       // 12544 floats per box
#define BC     16                   // channels per block
#define REG_R  16                   // region rows   (proven bound)
#define REG_C  20                   // region cols   (5 float4, proven bound)
#define NF4    5                    // float4 per region row
#define CH_STR (REG_R * REG_C + 4)  // 324 floats: +4 pad spreads banks, 16B-mult

__global__ __launch_bounds__(256) void roialign_kernel(
    const float* __restrict__ fm, const float* __restrict__ rois,
    const float* __restrict__ scale_p, float* __restrict__ out)
{
    __shared__ __align__(16) float s_reg[BC * CH_STR];     // 20736 B
    __shared__ int   s_yt[CROPN], s_yb[CROPN], s_xl[CROPN], s_xr[CROPN];
    __shared__ float s_ylerp[CROPN], s_vy[CROPN], s_xlerp[CROPN], s_vx[CROPN];

    const int t = threadIdx.x;

    // --- block -> (channel group, box) with XCD pinning ---
    const int bid  = blockIdx.x;
    const int numB = gridDim.x >> 4;           // = M
    const int xcd  = bid & 7;
    const int rb   = bid >> 3;                 // [0, 2M)
    const int cgl  = rb / numB;                // 0..1
    const int m    = rb - cgl * numB;          // box index
    const int c0   = (xcd * 2 + cgl) * BC;     // first channel (32-ch slab/XCD ~ L2-sized)

    const float scale = scale_p[0];
    const float* __restrict__ rr = rois + (size_t)m * 5;   // uniform -> s_load

    // --- geometry: threads 0..13 fill the per-sample tables (read after bar) ---
    if (t < 2 * CROPN) {
        // Replicate the reference's fp32 arithmetic exactly (no contraction).
        #pragma clang fp contract(off)
        {
            const int axis = (t >= CROPN) ? 1 : 0;   // 0 = y, 1 = x
            const int k = axis ? (t - CROPN) : t;
            float lo, hi, szm1;
            if (axis == 0) { lo = rr[2] * scale; hi = rr[4] * scale; szm1 = (float)(RA_H - 1); }
            else           { lo = rr[1] * scale; hi = rr[3] * scale; szm1 = (float)(RA_W - 1); }
            float sp   = (hi - lo) / 7.0f;
            float n0   = (lo + sp * 0.5f - 0.5f) / szm1;
            float nsz  = sp * 6.0f / szm1;
            float b2   = n0 + nsz;
            float d    = (b2 - n0) * szm1 / 6.0f;
            float coord = n0 * szm1 + (float)k * d;
            float fl = floorf(coord);
            float ce = ceilf(coord);
            float lerp = coord - fl;
            int lo_i = (int)fminf(fmaxf(fl, 0.0f), szm1);
            int hi_i = (int)fminf(fmaxf(ce, 0.0f), szm1);
            float valid = (coord >= 0.0f && coord <= szm1) ? 1.0f : 0.0f;
            if (axis == 0) {
                s_yt[k] = lo_i; s_yb[k] = hi_i;
                s_ylerp[k] = lerp; s_vy[k] = valid;
            } else {
                s_xl[k] = lo_i; s_xr[k] = hi_i;
                s_xlerp[k] = lerp; s_vx[k] = valid;
            }
        }
    }

    // --- every thread: region origin (bit-identical to k=0 geometry above) ---
    int ys, xs, base;
    {
        #pragma clang fp contract(off)
        float ylo = rr[2] * scale, yhi = rr[4] * scale;
        float xlo = rr[1] * scale, xhi = rr[3] * scale;
        float spy = (yhi - ylo) / 7.0f;
        float n0y = (ylo + spy * 0.5f - 0.5f) / 199.0f;
        float cy  = n0y * 199.0f;                       // == coord(y,k=0)
        float spx = (xhi - xlo) / 7.0f;
        float n0x = (xlo + spx * 0.5f - 0.5f) / 303.0f;
        float cx  = n0x * 303.0f;                       // == coord(x,k=0)
        ys = (int)fminf(fmaxf(floorf(cy), 0.0f), 199.0f);
        xs = ((int)fminf(fmaxf(floorf(cx), 0.0f), 303.0f)) & ~3;
        base = (int)rr[0] * RA_CHW + c0 * RA_HW;
    }

    // --- stage region: 5 independent f4 loads/thread, then 5 LDS writes ---
    const int cc  = t >> 4;                    // 0..15: one channel / 16 lanes
    const int l16 = t & 15;
    const float* __restrict__ cp = fm + (size_t)(base + cc * RA_HW);
    float4 v[NF4];
    #pragma unroll
    for (int s = 0; s < NF4; ++s) {
        const int idx = l16 + (s << 4);        // 0..79 : region f4 slot
        const int r2  = idx / 5;               // region row
        const int kk  = idx - r2 * 5;          // f4 within row
        const int row = min(ys + r2, RA_H - 1);        // clamp: dup rows, in-bounds
        const int col = min(xs + (kk << 2), RA_W - 4); // clamp: dup f4s, in-bounds
        v[s] = *reinterpret_cast<const float4*>(cp + row * RA_W + col);
    }
    {
        float* __restrict__ sp_ = s_reg + cc * CH_STR;
        #pragma unroll
        for (int s = 0; s < NF4; ++s) {
            const int idx = l16 + (s << 4);
            // float offset 4*idx == r2*REG_C + 4*kk (REG_C==20, NF4==5)
            *reinterpret_cast<float4*>(sp_ + (idx << 2)) = v[s];
        }
    }
    __syncthreads();   // single barrier: covers geometry tables + region

    // --- sampling: thread = (sample ij, 4-channel group) ---
    const int ij  = t & 63;                    // 49 active
    const int ch4 = t >> 6;                    // 0..3 -> channels 4*ch4..+3
    if (ij < CROP2) {
        const int i = ij / CROPN;
        const int j = ij - i * CROPN;
        const int rT = min(s_yt[i] - ys, REG_R - 1);
        const int rB = min(s_yb[i] - ys, REG_R - 1);
        const int cl = min(s_xl[j] - xs, REG_C - 1);
        const int cr = min(s_xr[j] - xs, REG_C - 1);
        const float yw = s_ylerp[i];
        const float xw = s_xlerp[j];
        const float vv = s_vy[i] * s_vx[j];
        const int oT = rT * REG_C;
        const int oB = rB * REG_C;
        float* __restrict__ op =
            out + (size_t)m * OUT_M + (size_t)(c0 + ch4 * 4) * CROP2 + ij;
        #pragma unroll
        for (int q = 0; q < 4; ++q) {
            const float* __restrict__ sp2 = s_reg + (ch4 * 4 + q) * CH_STR;
            const float tl = sp2[oT + cl];
            const float tr = sp2[oT + cr];
            const float bl = sp2[oB + cl];
            const float br = sp2[oB + cr];
            const float top = tl + (tr - tl) * xw;
            const float bot = bl + (br - bl) * xw;
            op[q * CROP2] = (top + (bot - top) * yw) * vv;
        }
    }
}

extern "C" void kernel_launch(void* const* d_in, const int* in_sizes, int n_in,
                              void* d_out, int out_size, void* d_ws, size_t ws_size,
                              hipStream_t stream) {
    const float* fm    = (const float*)d_in[0];
    const float* rois  = (const float*)d_in[1];
    const float* scale = (const float*)d_in[2];
    float* out = (float*)d_out;
    const int M = in_sizes[1] / 5;             // 2048
    roialign_kernel<<<dim3(16 * M), dim3(256), 0, stream>>>(fm, rois, scale, out);
}

// Round 3
// 268.397 us; speedup vs baseline: 1.0907x; 1.0907x over previous
//
#include <hip/hip_runtime.h>

// RoIAlign via TF crop_and_resize. Fixed problem shapes:
//   featuremap (N=2, C=256, H=200, W=304) fp32
//   rois       (M=2048, 5) fp32  [batch_id, x1, y1, x2, y2]
//   out        (M, C, 7, 7) fp32
//
// R2: XCD-pinned channel groups (fetch 382->194 MB).
// R4: per-thread scattered gathers (123 us) — TA-bound, 15% line util.
// R5: region staging BC=8 (139 us): right bytes (fetch 104 MB) but VGPR=8
//     -> serial load/ds_write round-trips, latency exposed.
// R6: BC=16 + v[5] register batch (143 us): pipeline fixed (3.47 TB/s!) but
//     16-ch slab = 7.8 MB > 4 MB XCD L2 -> fetch 382 MB (L2 thrash).
//     LESSON: channels-in-flight per XCD must be <= 8 (slab 3.9 MB < 4 MB).
// R7: both fixes together. Block = 2 boxes x 8 channels, 256 threads:
//     * 1280 f4 staging tasks = exactly 5/thread, v[5] register batch
//       (5 independent global_load_dwordx4 back-to-back, then 5 ds_writes).
//     * 8-channel XCD slab restored (32 cgl-sweeps, same as R5/R2).
//     * single barrier; loads issued BEFORE geometry-table phase so the
//       28-thread table math hides under load latency.
#define RA_C   256
#define RA_H   200
#define RA_W   304
#define RA_HW  (RA_H * RA_W)        // 60800
#define RA_CHW (RA_C * RA_HW)       // 15564800
#define CROPN  7
#define CROP2  (CROPN * CROPN)      // 49
#define OUT_M  (RA_C * CROP2)       // 12544 floats per box
#define BC     8                    // channels per block  (L2 slab constraint)
#define BB     2                    // boxes per block
#define REG_R  16                   // region rows   (proven bound)
#define REG_C  20                   // region cols   (5 float4, proven bound)
#define NF4    5                    // float4 per region row
#define CH_STR (REG_R * REG_C + 4)  // 324 floats: 16B-mult, +4 spreads banks

__global__ __launch_bounds__(256) void roialign_kernel(
    const float* __restrict__ fm, const float* __restrict__ rois,
    const float* __restrict__ scale_p, float* __restrict__ out)
{
    __shared__ __align__(16) float s_reg[BB * BC * CH_STR];     // 20736 B
    __shared__ int   s_yt[BB][CROPN], s_yb[BB][CROPN];
    __shared__ int   s_xl[BB][CROPN], s_xr[BB][CROPN];
    __shared__ float s_ylerp[BB][CROPN], s_vy[BB][CROPN];
    __shared__ float s_xlerp[BB][CROPN], s_vx[BB][CROPN];

    const int t = threadIdx.x;

    // --- block -> (channel group, box pair) with XCD pinning ---
    const int bid   = blockIdx.x;
    const int numBG = gridDim.x >> 5;          // M / BB
    const int xcd   = bid & 7;
    const int r     = bid >> 3;                // [0, 4*numBG)
    const int cgl   = r / numBG;               // [0, 4)
    const int bg    = r - cgl * numBG;         // [0, numBG)
    const int m0    = bg * BB;
    const int c0    = (xcd * 4 + cgl) * BC;    // 8-ch slab: 3.9 MB/XCD < 4 MB L2

    const int bx = t >> 7;                     // my box within the pair
    const float scale = scale_p[0];
    const float* __restrict__ rr = rois + (size_t)(m0 + bx) * 5;

    // --- region origin for my box (bit-identical to k=0 table geometry) ---
    int ys, xs, base;
    {
        #pragma clang fp contract(off)
        float ylo = rr[2] * scale, yhi = rr[4] * scale;
        float xlo = rr[1] * scale, xhi = rr[3] * scale;
        float spy = (yhi - ylo) / 7.0f;
        float n0y = (ylo + spy * 0.5f - 0.5f) / 199.0f;
        float cy  = n0y * 199.0f;                       // == coord(y, k=0)
        float spx = (xhi - xlo) / 7.0f;
        float n0x = (xlo + spx * 0.5f - 0.5f) / 303.0f;
        float cx  = n0x * 303.0f;                       // == coord(x, k=0)
        ys = (int)fminf(fmaxf(floorf(cy), 0.0f), 199.0f);
        xs = ((int)fminf(fmaxf(floorf(cx), 0.0f), 303.0f)) & ~3;
        base = (int)rr[0] * RA_CHW + c0 * RA_HW;        // < 2^31
    }

    // --- issue 5 independent f4 loads (register batch) ---
    const int u   = t & 127;
    const int cc  = u >> 4;                    // 0..7: one channel / 16 lanes
    const int l16 = u & 15;
    const float* __restrict__ cp = fm + (size_t)(base + cc * RA_HW);
    float4 v[NF4];
    #pragma unroll
    for (int s = 0; s < NF4; ++s) {
        const int idx = l16 + (s << 4);        // 0..79: region f4 slot
        const int r2  = idx / 5;               // region row
        const int kk  = idx - r2 * 5;          // f4 within row
        const int row = min(ys + r2, RA_H - 1);        // clamp: dup rows, in-bounds
        const int col = min(xs + (kk << 2), RA_W - 4); // clamp: dup f4s, in-bounds
        v[s] = *reinterpret_cast<const float4*>(cp + row * RA_W + col);
        // clamped duplicate slots are provably never sampled (abs col<=303,
        // abs row<=199 always map to un-clamped region indices).
    }

    // --- geometry tables: 28 threads, hidden under the loads above ---
    if (t < BB * 2 * CROPN) {
        // Replicate the reference's fp32 arithmetic exactly (no contraction).
        #pragma clang fp contract(off)
        {
            const int mm  = t / (2 * CROPN);
            const int k14 = t - mm * (2 * CROPN);
            const int axis = (k14 >= CROPN) ? 1 : 0;   // 0 = y, 1 = x
            const int k = axis ? (k14 - CROPN) : k14;
            const float* __restrict__ rg = rois + (size_t)(m0 + mm) * 5;
            float lo, hi, szm1;
            if (axis == 0) { lo = rg[2] * scale; hi = rg[4] * scale; szm1 = (float)(RA_H - 1); }
            else           { lo = rg[1] * scale; hi = rg[3] * scale; szm1 = (float)(RA_W - 1); }
            float sp   = (hi - lo) / 7.0f;
            float n0   = (lo + sp * 0.5f - 0.5f) / szm1;
            float nsz  = sp * 6.0f / szm1;
            float b2   = n0 + nsz;
            float d    = (b2 - n0) * szm1 / 6.0f;
            float coord = n0 * szm1 + (float)k * d;
            float fl = floorf(coord);
            float ce = ceilf(coord);
            float lerp = coord - fl;
            int lo_i = (int)fminf(fmaxf(fl, 0.0f), szm1);
            int hi_i = (int)fminf(fmaxf(ce, 0.0f), szm1);
            float valid = (coord >= 0.0f && coord <= szm1) ? 1.0f : 0.0f;
            if (axis == 0) {
                s_yt[mm][k] = lo_i; s_yb[mm][k] = hi_i;
                s_ylerp[mm][k] = lerp; s_vy[mm][k] = valid;
            } else {
                s_xl[mm][k] = lo_i; s_xr[mm][k] = hi_i;
                s_xlerp[mm][k] = lerp; s_vx[mm][k] = valid;
            }
        }
    }

    // --- drain loads into LDS (5 contiguous b128 writes) ---
    {
        float* __restrict__ sp_ = s_reg + (bx * BC + cc) * CH_STR;
        #pragma unroll
        for (int s = 0; s < NF4; ++s) {
            const int idx = l16 + (s << 4);
            // float offset 4*idx == r2*REG_C + 4*kk  (REG_C==20, NF4==5)
            *reinterpret_cast<float4*>(sp_ + (idx << 2)) = v[s];
        }
    }
    __syncthreads();   // single barrier: covers tables + region

    // --- sampling: thread = (box bx, sample ij, 4-channel group) ---
    const int ij  = t & 63;                    // 49 active
    const int chg = (t >> 6) & 1;              // 0..1 -> channels 4*chg..+3
    if (ij < CROP2) {
        const int i = ij / CROPN;
        const int j = ij - i * CROPN;
        const int rT = min(s_yt[bx][i] - ys, REG_R - 1);
        const int rB = min(s_yb[bx][i] - ys, REG_R - 1);
        const int cl = min(s_xl[bx][j] - xs, REG_C - 1);
        const int cr = min(s_xr[bx][j] - xs, REG_C - 1);
        const float yw = s_ylerp[bx][i];
        const float xw = s_xlerp[bx][j];
        const float vv = s_vy[bx][i] * s_vx[bx][j];
        const int oT = rT * REG_C;
        const int oB = rB * REG_C;
        float* __restrict__ op =
            out + (size_t)(m0 + bx) * OUT_M + (size_t)(c0 + chg * 4) * CROP2 + ij;
        #pragma unroll
        for (int q = 0; q < 4; ++q) {
            const float* __restrict__ sp2 =
                s_reg + (bx * BC + chg * 4 + q) * CH_STR;
            const float tl = sp2[oT + cl];
            const float tr = sp2[oT + cr];
            const float bl = sp2[oB + cl];
            const float br = sp2[oB + cr];
            const float top = tl + (tr - tl) * xw;
            const float bot = bl + (br - bl) * xw;
            op[q * CROP2] = (top + (bot - top) * yw) * vv;
        }
    }
}

extern "C" void kernel_launch(void* const* d_in, const int* in_sizes, int n_in,
                              void* d_out, int out_size, void* d_ws, size_t ws_size,
                              hipStream_t stream) {
    const float* fm    = (const float*)d_in[0];
    const float* rois  = (const float*)d_in[1];
    const float* scale = (const float*)d_in[2];
    float* out = (float*)d_out;
    const int M = in_sizes[1] / 5;             // 2048
    const int numBG = M / BB;                  // 1024
    roialign_kernel<<<dim3(32 * numBG), dim3(256), 0, stream>>>(fm, rois, scale, out);
}